// Round 1
// baseline (264.624 us; speedup 1.0000x reference)
//
#include <hip/hip_runtime.h>

#define DEV __device__ __forceinline__

DEV float crelu(float x) { return fminf(fmaxf(x, -1.0f), 1.0f); }

// ---------------------------------------------------------------------------
// Prep: transpose weights into d_ws so the inner loops read contiguous rows
// with wave-uniform indices (-> s_load_dwordx8/16, constant-cache resident).
// ws layout (floats):
//   w1t [54][16] @ 0     (864)   w1t[s*16+o]   = W1[o*54+s]
//   w2t [16][16] @ 864   (256)   w2t[i*16+o]   = W2[o*16+i]
//   w3t [16][2]  @ 1120  (32)    w3t[i*2+o]    = W3[o*16+i]
//   e1t [73][34] @ 1152  (2482)  e1t[i*34+o]   = E1[o*73+i]
//   e2t [34][34] @ 3634  (1156)  e2t[i*34+o]   = E2[o*34+i]
// total 4790 floats = 19160 bytes
// ---------------------------------------------------------------------------
__global__ void prep_kernel(const float* __restrict__ W1, const float* __restrict__ W2,
                            const float* __restrict__ W3, const float* __restrict__ E1,
                            const float* __restrict__ E2, float* __restrict__ ws) {
    int t = threadIdx.x + blockIdx.x * blockDim.x;
    if (t < 864) {
        int s = t >> 4, o = t & 15;
        ws[t] = W1[o * 54 + s];
    } else if (t < 864 + 256) {
        int u = t - 864; int i = u >> 4, o = u & 15;
        ws[t] = W2[o * 16 + i];
    } else if (t < 1120 + 32) {
        int u = t - 1120; int i = u >> 1, o = u & 1;
        ws[t] = W3[o * 16 + i];
    } else if (t < 1152 + 2482) {
        int u = t - 1152; int i = u / 34, o = u % 34;
        ws[t] = E1[o * 73 + i];
    } else if (t < 3634 + 1156) {
        int u = t - 3634; int i = u / 34, o = u % 34;
        ws[t] = E2[o * 34 + i];
    }
}

// ---------------------------------------------------------------------------
// Main: one thread per batch element. Head layer 1 (E1) is accumulated on the
// fly per window so v[72] never exists as a runtime-indexed register array.
// ---------------------------------------------------------------------------
__global__ __launch_bounds__(256) void lila_kernel(
    const float* __restrict__ inp,
    const float* __restrict__ b1, const float* __restrict__ b2,
    const float* __restrict__ b3,
    const float* __restrict__ e1, const float* __restrict__ e2,
    const float* __restrict__ E3, const float* __restrict__ e3,
    const float* __restrict__ ws, float* __restrict__ out)
{
    const int e = threadIdx.x + blockIdx.x * 256;
    const float* __restrict__ in_e = inp + (size_t)e * 385;
    const float* __restrict__ w1t = ws;            // [54][16]
    const float* __restrict__ w2t = ws + 864;      // [16][16]
    const float* __restrict__ w3t = ws + 1120;     // [16][2]
    const float* __restrict__ e1t = ws + 1152;     // [73][34]
    const float* __restrict__ e2t = ws + 3634;     // [34][34]

    // head layer-1 accumulators (fused E1)
    float a1[34];
    #pragma unroll
    for (int o = 0; o < 34; ++o) a1[o] = e1[o];

    #pragma unroll 1
    for (int x = 0; x < 6; ++x) {
        #pragma unroll 1
        for (int y = 0; y < 6; ++y) {
            // ---- layer 1: 54 -> 16 ----
            float acc[16];
            #pragma unroll
            for (int o = 0; o < 16; ++o) acc[o] = b1[o];
            #pragma unroll
            for (int ox = 0; ox < 3; ++ox) {
                const float* __restrict__ p = in_e + (x + ox) * 48 + y * 6;
                float seg[18];
                #pragma unroll
                for (int k = 0; k < 18; ++k) seg[k] = p[k];
                #pragma unroll
                for (int k = 0; k < 18; ++k) {
                    const float xs = seg[k];
                    const float* __restrict__ wr = w1t + (ox * 18 + k) * 16;
                    #pragma unroll
                    for (int o = 0; o < 16; ++o) acc[o] = fmaf(xs, wr[o], acc[o]);
                }
            }
            // ---- layer 2: 16 -> 16 ----
            float h2[16];
            #pragma unroll
            for (int o = 0; o < 16; ++o) h2[o] = b2[o];
            #pragma unroll
            for (int i = 0; i < 16; ++i) {
                const float hi = crelu(acc[i]);
                const float* __restrict__ wr = w2t + i * 16;
                #pragma unroll
                for (int o = 0; o < 16; ++o) h2[o] = fmaf(hi, wr[o], h2[o]);
            }
            // ---- layer 3: 16 -> 2 ----
            float v0 = b3[0], v1 = b3[1];
            #pragma unroll
            for (int i = 0; i < 16; ++i) {
                const float hi = crelu(h2[i]);
                v0 = fmaf(hi, w3t[i * 2 + 0], v0);
                v1 = fmaf(hi, w3t[i * 2 + 1], v1);
            }
            v0 = crelu(v0); v1 = crelu(v1);
            // ---- fused head E1 accumulation for this window ----
            const int w = x * 6 + y;
            const float* __restrict__ r0 = e1t + (2 * w) * 34;
            const float* __restrict__ r1 = e1t + (2 * w + 1) * 34;
            #pragma unroll
            for (int o = 0; o < 34; ++o)
                a1[o] = fmaf(v1, r1[o], fmaf(v0, r0[o], a1[o]));
        }
    }

    // ---- vision[72] = inp[384] term, then clamp head layer 1 ----
    const float xl = in_e[384];
    const float* __restrict__ rl = e1t + 72 * 34;

    // ---- head layer 2: 34 -> 34 ----
    float a2[34];
    #pragma unroll
    for (int o = 0; o < 34; ++o) a2[o] = e2[o];
    #pragma unroll 1
    for (int i = 0; i < 34; ++i) {
        const float hi = crelu(fmaf(xl, rl[i], a1[i]));
        const float* __restrict__ wr = e2t + i * 34;
        #pragma unroll
        for (int o = 0; o < 34; ++o) a2[o] = fmaf(hi, wr[o], a2[o]);
    }
    // ---- head layer 3: 34 -> 1 ----
    float r = e3[0];
    #pragma unroll
    for (int i = 0; i < 34; ++i) r = fmaf(crelu(a2[i]), E3[i], r);
    out[e] = crelu(r);
}

extern "C" void kernel_launch(void* const* d_in, const int* in_sizes, int n_in,
                              void* d_out, int out_size, void* d_ws, size_t ws_size,
                              hipStream_t stream) {
    const float* inp = (const float*)d_in[0];
    const float* W1  = (const float*)d_in[1];
    const float* b1  = (const float*)d_in[2];
    const float* W2  = (const float*)d_in[3];
    const float* b2  = (const float*)d_in[4];
    const float* W3  = (const float*)d_in[5];
    const float* b3  = (const float*)d_in[6];
    const float* E1  = (const float*)d_in[7];
    const float* e1  = (const float*)d_in[8];
    const float* E2  = (const float*)d_in[9];
    const float* e2  = (const float*)d_in[10];
    const float* E3  = (const float*)d_in[11];
    const float* e3  = (const float*)d_in[12];
    float* out = (float*)d_out;
    float* ws  = (float*)d_ws;

    // transpose weights into ws (4790 floats)
    prep_kernel<<<(4790 + 255) / 256, 256, 0, stream>>>(W1, W2, W3, E1, E2, ws);

    const int B = 65536;
    lila_kernel<<<B / 256, 256, 0, stream>>>(inp, b1, b2, b3, e1, e2, E3, e3, ws, out);
}

// Round 2
// 246.057 us; speedup vs baseline: 1.0755x; 1.0755x over previous
//
#include <hip/hip_runtime.h>

#define DEV __device__ __forceinline__

DEV float crelu(float x) { return fminf(fmaxf(x, -1.0f), 1.0f); }

// ---------------------------------------------------------------------------
// Prep: transpose weights into d_ws.
// ws layout (floats):
//   w1t [54][16] @ 0     (864)   w1t[s*16+o]   = W1[o*54+s]
//   w2t [16][16] @ 864   (256)   w2t[i*16+o]   = W2[o*16+i]
//   w3t [16][2]  @ 1120  (32)    w3t[i*2+o]    = W3[o*16+i]
//   e1t [73][34] @ 1152  (2482)  e1t[c*34+o]   = E1[o*73+c]   (16B-aligned rows pairs)
//   e2t [34][34] @ 3634  (1156)  e2t[i*34+o]   = E2[o*34+i]
// ---------------------------------------------------------------------------
__global__ void prep_kernel(const float* __restrict__ W1, const float* __restrict__ W2,
                            const float* __restrict__ W3, const float* __restrict__ E1,
                            const float* __restrict__ E2, float* __restrict__ ws) {
    int t = threadIdx.x + blockIdx.x * blockDim.x;
    if (t < 864) {
        int s = t >> 4, o = t & 15;
        ws[t] = W1[o * 54 + s];
    } else if (t < 864 + 256) {
        int u = t - 864; int i = u >> 4, o = u & 15;
        ws[t] = W2[o * 16 + i];
    } else if (t < 1120 + 32) {
        int u = t - 1120; int i = u >> 1, o = u & 1;
        ws[t] = W3[o * 16 + i];
    } else if (t < 1152 + 2482) {
        int u = t - 1152; int c = u / 34, o = u % 34;
        ws[t] = E1[o * 73 + c];
    } else if (t < 3634 + 1156) {
        int u = t - 3634; int i = u / 34, o = u % 34;
        ws[t] = E2[o * 34 + i];
    }
}

// ---------------------------------------------------------------------------
// Main: TWO threads per batch element (lanes 2i / 2i+1 of a wave).
//   s = t&1 selects y-half: windows y in {3s, 3s+1, 3s+2}.
//   x loop rolled 0..5, rolling 3-row register window (30 cols each).
//   Each input float is loaded exactly once per thread.
//   Fused E1 accumulation per window via per-lane float4 weight loads.
//   a1 reduced across the lane pair with __shfl_xor; head redundant on both.
// ---------------------------------------------------------------------------
__global__ __launch_bounds__(256, 2) void lila_kernel(
    const float* __restrict__ inp,
    const float* __restrict__ b1, const float* __restrict__ b2,
    const float* __restrict__ b3,
    const float* __restrict__ e1, const float* __restrict__ e2,
    const float* __restrict__ E3, const float* __restrict__ e3,
    const float* __restrict__ ws, float* __restrict__ out)
{
    const int t = threadIdx.x + blockIdx.x * 256;
    const int p = t >> 1;      // element
    const int s = t & 1;       // y-half
    const float* __restrict__ in_e = inp + (size_t)p * 385;
    const float* __restrict__ w1t = ws;            // [54][16]
    const float* __restrict__ w2t = ws + 864;      // [16][16]
    const float* __restrict__ w3t = ws + 1120;     // [16][2]
    const float* __restrict__ e1t = ws + 1152;     // [73][34]
    const float* __restrict__ e2t = ws + 3634;     // [34][34]
    const int cbase = 18 * s;  // column base within each 48-float row

    // rolling 3-row register window
    float R0[30], R1[30], R2[30];
    #pragma unroll
    for (int c = 0; c < 30; ++c) R0[c] = in_e[0 * 48 + cbase + c];
    #pragma unroll
    for (int c = 0; c < 30; ++c) R1[c] = in_e[1 * 48 + cbase + c];

    // fused-E1 accumulators (bias counted once, on lane s==0)
    float a1[34];
    #pragma unroll
    for (int o = 0; o < 34; ++o) a1[o] = s ? 0.0f : e1[o];

    #pragma unroll 1
    for (int x = 0; x < 6; ++x) {
        // prefetch row x+2
        #pragma unroll
        for (int c = 0; c < 30; ++c) R2[c] = in_e[(x + 2) * 48 + cbase + c];

        #pragma unroll
        for (int yl = 0; yl < 3; ++yl) {
            // ---- layer 1: 54 -> 16 ----
            float acc[16];
            #pragma unroll
            for (int o = 0; o < 16; ++o) acc[o] = b1[o];
            #pragma unroll
            for (int ox = 0; ox < 3; ++ox) {
                const float* __restrict__ Rr = (ox == 0) ? R0 : (ox == 1) ? R1 : R2;
                #pragma unroll
                for (int k = 0; k < 18; ++k) {
                    const float xs = Rr[yl * 6 + k];
                    const float* __restrict__ wr = w1t + (ox * 18 + k) * 16;
                    #pragma unroll
                    for (int o = 0; o < 16; ++o) acc[o] = fmaf(xs, wr[o], acc[o]);
                }
            }
            // ---- layer 2: 16 -> 16 ----
            float h2[16];
            #pragma unroll
            for (int o = 0; o < 16; ++o) h2[o] = b2[o];
            #pragma unroll
            for (int i = 0; i < 16; ++i) {
                const float hi = crelu(acc[i]);
                const float* __restrict__ wr = w2t + i * 16;
                #pragma unroll
                for (int o = 0; o < 16; ++o) h2[o] = fmaf(hi, wr[o], h2[o]);
            }
            // ---- layer 3: 16 -> 2 ----
            float v0 = b3[0], v1 = b3[1];
            #pragma unroll
            for (int i = 0; i < 16; ++i) {
                const float hi = crelu(h2[i]);
                v0 = fmaf(hi, w3t[i * 2 + 0], v0);
                v1 = fmaf(hi, w3t[i * 2 + 1], v1);
            }
            v0 = crelu(v0); v1 = crelu(v1);
            // ---- fused head E1 accumulation for this window ----
            // window index depends on s -> per-lane float4 loads (L1-resident)
            const int w = x * 6 + (3 * s + yl);
            const float4* __restrict__ c4 =
                reinterpret_cast<const float4*>(e1t + (size_t)w * 68);
            #pragma unroll
            for (int j = 0; j < 17; ++j) {
                const float4 q = c4[j];
                #pragma unroll
                for (int u = 0; u < 4; ++u) {
                    const int f = 4 * j + u;
                    const float qv = (u == 0) ? q.x : (u == 1) ? q.y : (u == 2) ? q.z : q.w;
                    if (f < 34) a1[f]      = fmaf(v0, qv, a1[f]);
                    else        a1[f - 34] = fmaf(v1, qv, a1[f - 34]);
                }
            }
        }

        // rotate rows
        #pragma unroll
        for (int c = 0; c < 30; ++c) { R0[c] = R1[c]; R1[c] = R2[c]; }
    }

    // ---- reduce a1 across the lane pair (both lanes end with the sum) ----
    #pragma unroll
    for (int o = 0; o < 34; ++o) a1[o] += __shfl_xor(a1[o], 1);

    // ---- vision[72] = inp[384] term ----
    const float xl = in_e[384];
    const float* __restrict__ rl = e1t + 72 * 34;

    // ---- head layer 2: 34 -> 34 (redundant on both lanes, uniform weights) ----
    float a2[34];
    #pragma unroll
    for (int o = 0; o < 34; ++o) a2[o] = e2[o];
    #pragma unroll 1
    for (int i = 0; i < 34; ++i) {
        const float hi = crelu(fmaf(xl, rl[i], a1[i]));
        const float* __restrict__ wr = e2t + i * 34;
        #pragma unroll
        for (int o = 0; o < 34; ++o) a2[o] = fmaf(hi, wr[o], a2[o]);
    }
    // ---- head layer 3: 34 -> 1 ----
    float r = e3[0];
    #pragma unroll
    for (int i = 0; i < 34; ++i) r = fmaf(crelu(a2[i]), E3[i], r);
    if (s == 0) out[p] = crelu(r);
}

extern "C" void kernel_launch(void* const* d_in, const int* in_sizes, int n_in,
                              void* d_out, int out_size, void* d_ws, size_t ws_size,
                              hipStream_t stream) {
    const float* inp = (const float*)d_in[0];
    const float* W1  = (const float*)d_in[1];
    const float* b1  = (const float*)d_in[2];
    const float* W2  = (const float*)d_in[3];
    const float* b2  = (const float*)d_in[4];
    const float* W3  = (const float*)d_in[5];
    const float* b3  = (const float*)d_in[6];
    const float* E1  = (const float*)d_in[7];
    const float* e1  = (const float*)d_in[8];
    const float* E2  = (const float*)d_in[9];
    const float* e2  = (const float*)d_in[10];
    const float* E3  = (const float*)d_in[11];
    const float* e3  = (const float*)d_in[12];
    float* out = (float*)d_out;
    float* ws  = (float*)d_ws;

    prep_kernel<<<(4790 + 255) / 256, 256, 0, stream>>>(W1, W2, W3, E1, E2, ws);

    const int B = 65536;
    lila_kernel<<<(B * 2) / 256, 256, 0, stream>>>(inp, b1, b2, b3, e1, e2, E3, e3, ws, out);
}

// Round 3
// 232.905 us; speedup vs baseline: 1.1362x; 1.0565x over previous
//
#include <hip/hip_runtime.h>
#include <hip/hip_fp16.h>

#define DEV __device__ __forceinline__

DEV float crelu(float x) { return fminf(fmaxf(x, -1.0f), 1.0f); }

// ---------------------------------------------------------------------------
// ws layout:
//   floats 0..4789: transposed weights
//     w1t [54][16] @ 0      w1t[s*16+o] = W1[o*54+s]
//     w2t [16][16] @ 864    w2t[i*16+o] = W2[o*16+i]
//     w3t [16][2]  @ 1120   w3t[i*2+o]  = W3[o*16+i]
//     e1t [73][34] @ 1152   e1t[c*34+o] = E1[o*73+c]
//     e2t [34][34] @ 3634   e2t[i*34+o] = E2[o*34+i]
//   byte 32768: v-buffer, [B][36] __half2  (9.44 MB)
// ---------------------------------------------------------------------------
__global__ void prep_kernel(const float* __restrict__ W1, const float* __restrict__ W2,
                            const float* __restrict__ W3, const float* __restrict__ E1,
                            const float* __restrict__ E2, float* __restrict__ ws) {
    int t = threadIdx.x + blockIdx.x * blockDim.x;
    if (t < 864) {
        int s = t >> 4, o = t & 15;
        ws[t] = W1[o * 54 + s];
    } else if (t < 864 + 256) {
        int u = t - 864; int i = u >> 4, o = u & 15;
        ws[t] = W2[o * 16 + i];
    } else if (t < 1120 + 32) {
        int u = t - 1120; int i = u >> 1, o = u & 1;
        ws[t] = W3[o * 16 + i];
    } else if (t < 1152 + 2482) {
        int u = t - 1152; int c = u / 34, o = u % 34;
        ws[t] = E1[o * 73 + c];
    } else if (t < 3634 + 1156) {
        int u = t - 3634; int i = u / 34, o = u % 34;
        ws[t] = E2[o * 34 + i];
    }
}

// ---------------------------------------------------------------------------
// Phase 1: one thread per (element, window). 2.36M threads.
// 54 -> 16 -> 16 -> 2, weights wave-uniform (s_load), result as __half2.
// ---------------------------------------------------------------------------
__global__ __launch_bounds__(256) void win_kernel(
    const float* __restrict__ inp,
    const float* __restrict__ b1, const float* __restrict__ b2,
    const float* __restrict__ b3,
    const float* __restrict__ ws, __half2* __restrict__ vout)
{
    const int t = threadIdx.x + blockIdx.x * 256;
    const int p = t / 36;          // element
    const int w = t - p * 36;      // window 0..35
    const int x = w / 6;
    const int y = w - x * 6;
    const float* __restrict__ in_e = inp + (size_t)p * 385 + x * 48 + y * 6;
    const float* __restrict__ w1t = ws;
    const float* __restrict__ w2t = ws + 864;
    const float* __restrict__ w3t = ws + 1120;

    // load the 3x18 input patch
    float r[54];
    #pragma unroll
    for (int ox = 0; ox < 3; ++ox)
        #pragma unroll
        for (int k = 0; k < 18; ++k)
            r[ox * 18 + k] = in_e[ox * 48 + k];

    // ---- layer 1: 54 -> 16 ----
    float acc[16];
    #pragma unroll
    for (int o = 0; o < 16; ++o) acc[o] = b1[o];
    #pragma unroll
    for (int k = 0; k < 54; ++k) {
        const float xs = r[k];
        const float* __restrict__ wr = w1t + k * 16;
        #pragma unroll
        for (int o = 0; o < 16; ++o) acc[o] = fmaf(xs, wr[o], acc[o]);
    }
    // ---- layer 2: 16 -> 16 ----
    float h2[16];
    #pragma unroll
    for (int o = 0; o < 16; ++o) h2[o] = b2[o];
    #pragma unroll
    for (int i = 0; i < 16; ++i) {
        const float hi = crelu(acc[i]);
        const float* __restrict__ wr = w2t + i * 16;
        #pragma unroll
        for (int o = 0; o < 16; ++o) h2[o] = fmaf(hi, wr[o], h2[o]);
    }
    // ---- layer 3: 16 -> 2 ----
    float v0 = b3[0], v1 = b3[1];
    #pragma unroll
    for (int i = 0; i < 16; ++i) {
        const float hi = crelu(h2[i]);
        v0 = fmaf(hi, w3t[i * 2 + 0], v0);
        v1 = fmaf(hi, w3t[i * 2 + 1], v1);
    }
    __half2 hv;
    hv.x = __float2half(crelu(v0));
    hv.y = __float2half(crelu(v1));
    vout[t] = hv;
}

// ---------------------------------------------------------------------------
// Phase 2: two threads per element. Lane s handles E1 input columns
// [36s, 36s+36) (s==1 also takes column 72 = inp[384]); shfl-reduce the
// 34 partials; E2/E3 redundant on both lanes (wave-uniform weights).
// All register arrays statically indexed (fully unrolled).
// ---------------------------------------------------------------------------
__global__ __launch_bounds__(256) void head_kernel(
    const float* __restrict__ inp,
    const float* __restrict__ e1, const float* __restrict__ e2,
    const float* __restrict__ E3, const float* __restrict__ e3,
    const float* __restrict__ ws, const __half* __restrict__ v,
    float* __restrict__ out)
{
    const int t = threadIdx.x + blockIdx.x * 256;
    const int p = t >> 1;
    const int s = t & 1;
    const float* __restrict__ e1t = ws + 1152;
    const float* __restrict__ e2t = ws + 3634;

    // load this lane's 36 vision values
    float vi[36];
    const __half2* __restrict__ vh =
        reinterpret_cast<const __half2*>(v + (size_t)p * 72 + s * 36);
    #pragma unroll
    for (int j = 0; j < 18; ++j) {
        const __half2 q = vh[j];
        vi[2 * j]     = __half2float(q.x);
        vi[2 * j + 1] = __half2float(q.y);
    }

    // ---- head layer 1: partial over this lane's 36 columns ----
    float a1[34];
    #pragma unroll
    for (int o = 0; o < 34; ++o) a1[o] = s ? 0.0f : e1[o];
    const int cbase = 36 * s;
    #pragma unroll
    for (int i = 0; i < 36; ++i) {
        const float hi = vi[i];
        const float* __restrict__ wr = e1t + (cbase + i) * 34;
        #pragma unroll
        for (int o = 0; o < 34; ++o) a1[o] = fmaf(hi, wr[o], a1[o]);
    }
    if (s) {
        const float xl = inp[(size_t)p * 385 + 384];
        const float* __restrict__ rl = e1t + 72 * 34;
        #pragma unroll
        for (int o = 0; o < 34; ++o) a1[o] = fmaf(xl, rl[o], a1[o]);
    }
    #pragma unroll
    for (int o = 0; o < 34; ++o) a1[o] += __shfl_xor(a1[o], 1);

    // ---- head layer 2: 34 -> 34 (redundant on both lanes) ----
    float a2[34];
    #pragma unroll
    for (int o = 0; o < 34; ++o) a2[o] = e2[o];
    #pragma unroll
    for (int i = 0; i < 34; ++i) {
        const float hi = crelu(a1[i]);
        const float* __restrict__ wr = e2t + i * 34;
        #pragma unroll
        for (int o = 0; o < 34; ++o) a2[o] = fmaf(hi, wr[o], a2[o]);
    }
    // ---- head layer 3: 34 -> 1 ----
    float rr = e3[0];
    #pragma unroll
    for (int i = 0; i < 34; ++i) rr = fmaf(crelu(a2[i]), E3[i], rr);
    if (!s) out[p] = crelu(rr);
}

extern "C" void kernel_launch(void* const* d_in, const int* in_sizes, int n_in,
                              void* d_out, int out_size, void* d_ws, size_t ws_size,
                              hipStream_t stream) {
    const float* inp = (const float*)d_in[0];
    const float* W1  = (const float*)d_in[1];
    const float* b1  = (const float*)d_in[2];
    const float* W2  = (const float*)d_in[3];
    const float* b2  = (const float*)d_in[4];
    const float* W3  = (const float*)d_in[5];
    const float* b3  = (const float*)d_in[6];
    const float* E1  = (const float*)d_in[7];
    const float* e1  = (const float*)d_in[8];
    const float* E2  = (const float*)d_in[9];
    const float* e2  = (const float*)d_in[10];
    const float* E3  = (const float*)d_in[11];
    const float* e3  = (const float*)d_in[12];
    float* out = (float*)d_out;
    float* ws  = (float*)d_ws;
    __half* vbuf = (__half*)((char*)d_ws + 32768);

    prep_kernel<<<(4790 + 255) / 256, 256, 0, stream>>>(W1, W2, W3, E1, E2, ws);

    const int B = 65536;
    // phase 1: B*36 threads, exactly 9216 blocks of 256
    win_kernel<<<(B * 36) / 256, 256, 0, stream>>>(inp, b1, b2, b3, ws,
                                                   (__half2*)vbuf);
    // phase 2: B*2 threads
    head_kernel<<<(B * 2) / 256, 256, 0, stream>>>(inp, e1, e2, E3, e3, ws,
                                                   vbuf, out);
}

// Round 4
// 124.018 us; speedup vs baseline: 2.1337x; 1.8780x over previous
//
#include <hip/hip_runtime.h>
#include <hip/hip_fp16.h>

#define DEV __device__ __forceinline__

DEV float crelu(float x) { return fminf(fmaxf(x, -1.0f), 1.0f); }

// ---------------------------------------------------------------------------
// ws layout:
//   floats 0..4789: transposed weights
//     w1t [54][16] @ 0      w1t[s*16+o] = W1[o*54+s]
//     w2t [16][16] @ 864    w2t[i*16+o] = W2[o*16+i]
//     w3t [16][2]  @ 1120   w3t[i*2+o]  = W3[o*16+i]
//     e1t [73][34] @ 1152   e1t[c*34+o] = E1[o*73+c]
//     e2t [34][34] @ 3634   e2t[i*34+o] = E2[o*34+i]
//   byte 32768: v-buffer, [B][36] __half2  (9.44 MB)
// ---------------------------------------------------------------------------
__global__ void prep_kernel(const float* __restrict__ W1, const float* __restrict__ W2,
                            const float* __restrict__ W3, const float* __restrict__ E1,
                            const float* __restrict__ E2, float* __restrict__ ws) {
    int t = threadIdx.x + blockIdx.x * blockDim.x;
    if (t < 864) {
        int s = t >> 4, o = t & 15;
        ws[t] = W1[o * 54 + s];
    } else if (t < 864 + 256) {
        int u = t - 864; int i = u >> 4, o = u & 15;
        ws[t] = W2[o * 16 + i];
    } else if (t < 1120 + 32) {
        int u = t - 1120; int i = u >> 1, o = u & 1;
        ws[t] = W3[o * 16 + i];
    } else if (t < 1152 + 2482) {
        int u = t - 1152; int c = u / 34, o = u % 34;
        ws[t] = E1[o * 73 + c];
    } else if (t < 3634 + 1156) {
        int u = t - 3634; int i = u / 34, o = u % 34;
        ws[t] = E2[o * 34 + i];
    }
}

// ---------------------------------------------------------------------------
// Phase 1: one thread per (element, window). 2.36M threads.
// 54 -> 16 -> 16 -> 2, weights wave-uniform (s_load), result as __half2.
// ---------------------------------------------------------------------------
__global__ __launch_bounds__(256) void win_kernel(
    const float* __restrict__ inp,
    const float* __restrict__ b1, const float* __restrict__ b2,
    const float* __restrict__ b3,
    const float* __restrict__ ws, __half2* __restrict__ vout)
{
    const int t = threadIdx.x + blockIdx.x * 256;
    const int p = t / 36;          // element
    const int w = t - p * 36;      // window 0..35
    const int x = w / 6;
    const int y = w - x * 6;
    const float* __restrict__ in_e = inp + (size_t)p * 385 + x * 48 + y * 6;
    const float* __restrict__ w1t = ws;
    const float* __restrict__ w2t = ws + 864;
    const float* __restrict__ w3t = ws + 1120;

    // load the 3x18 input patch
    float r[54];
    #pragma unroll
    for (int ox = 0; ox < 3; ++ox)
        #pragma unroll
        for (int k = 0; k < 18; ++k)
            r[ox * 18 + k] = in_e[ox * 48 + k];

    // ---- layer 1: 54 -> 16 ----
    float acc[16];
    #pragma unroll
    for (int o = 0; o < 16; ++o) acc[o] = b1[o];
    #pragma unroll
    for (int k = 0; k < 54; ++k) {
        const float xs = r[k];
        const float* __restrict__ wr = w1t + k * 16;
        #pragma unroll
        for (int o = 0; o < 16; ++o) acc[o] = fmaf(xs, wr[o], acc[o]);
    }
    // ---- layer 2: 16 -> 16 ----
    float h2[16];
    #pragma unroll
    for (int o = 0; o < 16; ++o) h2[o] = b2[o];
    #pragma unroll
    for (int i = 0; i < 16; ++i) {
        const float hi = crelu(acc[i]);
        const float* __restrict__ wr = w2t + i * 16;
        #pragma unroll
        for (int o = 0; o < 16; ++o) h2[o] = fmaf(hi, wr[o], h2[o]);
    }
    // ---- layer 3: 16 -> 2 ----
    float v0 = b3[0], v1 = b3[1];
    #pragma unroll
    for (int i = 0; i < 16; ++i) {
        const float hi = crelu(h2[i]);
        v0 = fmaf(hi, w3t[i * 2 + 0], v0);
        v1 = fmaf(hi, w3t[i * 2 + 1], v1);
    }
    __half2 hv;
    hv.x = __float2half(crelu(v0));
    hv.y = __float2half(crelu(v1));
    vout[t] = hv;
}

// ---------------------------------------------------------------------------
// Phase 2: ONE thread per element. Every weight access is lane-uniform with
// compile-time offsets -> scalar loads through the constant cache (batched
// s_load_dwordxN), zero VMEM on the weight path. Vision vector read as
// 9 x 16B packed-half loads and converted on the fly.
// ---------------------------------------------------------------------------
struct V8 { __half2 a, b, c, d; };   // 16 bytes = 8 halfs

__global__ __launch_bounds__(256, 1) void head_kernel(
    const float* __restrict__ inp,
    const float* __restrict__ e1, const float* __restrict__ e2,
    const float* __restrict__ E3, const float* __restrict__ e3,
    const float* __restrict__ ws, const __half* __restrict__ v,
    float* __restrict__ out)
{
    const int p = threadIdx.x + blockIdx.x * 256;   // element
    const float* __restrict__ e1t = ws + 1152;
    const float* __restrict__ e2t = ws + 3634;

    // ---- load vision[72] as 9 x 16B, unpack to fp32 ----
    const V8* __restrict__ vp = reinterpret_cast<const V8*>(v + (size_t)p * 72);
    float vc[72];
    #pragma unroll
    for (int j = 0; j < 9; ++j) {
        const V8 q = vp[j];
        vc[8 * j + 0] = __low2float(q.a);  vc[8 * j + 1] = __high2float(q.a);
        vc[8 * j + 2] = __low2float(q.b);  vc[8 * j + 3] = __high2float(q.b);
        vc[8 * j + 4] = __low2float(q.c);  vc[8 * j + 5] = __high2float(q.c);
        vc[8 * j + 6] = __low2float(q.d);  vc[8 * j + 7] = __high2float(q.d);
    }
    const float xl = inp[(size_t)p * 385 + 384];    // vision[72]

    // ---- head layer 1: 73 -> 34 (weights uniform -> s_load) ----
    float a1[34];
    #pragma unroll
    for (int o = 0; o < 34; ++o) a1[o] = e1[o];
    #pragma unroll
    for (int c = 0; c < 72; ++c) {
        const float xc = vc[c];
        const float* __restrict__ wr = e1t + c * 34;
        #pragma unroll
        for (int o = 0; o < 34; ++o) a1[o] = fmaf(xc, wr[o], a1[o]);
    }
    {
        const float* __restrict__ wr = e1t + 72 * 34;
        #pragma unroll
        for (int o = 0; o < 34; ++o) a1[o] = fmaf(xl, wr[o], a1[o]);
    }

    // ---- head layer 2: 34 -> 34 ----
    float a2[34];
    #pragma unroll
    for (int o = 0; o < 34; ++o) a2[o] = e2[o];
    #pragma unroll
    for (int i = 0; i < 34; ++i) {
        const float hi = crelu(a1[i]);
        const float* __restrict__ wr = e2t + i * 34;
        #pragma unroll
        for (int o = 0; o < 34; ++o) a2[o] = fmaf(hi, wr[o], a2[o]);
    }
    // ---- head layer 3: 34 -> 1 ----
    float rr = e3[0];
    #pragma unroll
    for (int i = 0; i < 34; ++i) rr = fmaf(crelu(a2[i]), E3[i], rr);
    out[p] = crelu(rr);
}

extern "C" void kernel_launch(void* const* d_in, const int* in_sizes, int n_in,
                              void* d_out, int out_size, void* d_ws, size_t ws_size,
                              hipStream_t stream) {
    const float* inp = (const float*)d_in[0];
    const float* W1  = (const float*)d_in[1];
    const float* b1  = (const float*)d_in[2];
    const float* W2  = (const float*)d_in[3];
    const float* b2  = (const float*)d_in[4];
    const float* W3  = (const float*)d_in[5];
    const float* b3  = (const float*)d_in[6];
    const float* E1  = (const float*)d_in[7];
    const float* e1  = (const float*)d_in[8];
    const float* E2  = (const float*)d_in[9];
    const float* e2  = (const float*)d_in[10];
    const float* E3  = (const float*)d_in[11];
    const float* e3  = (const float*)d_in[12];
    float* out = (float*)d_out;
    float* ws  = (float*)d_ws;
    __half* vbuf = (__half*)((char*)d_ws + 32768);

    prep_kernel<<<(4790 + 255) / 256, 256, 0, stream>>>(W1, W2, W3, E1, E2, ws);

    const int B = 65536;
    // phase 1: B*36 threads, exactly 9216 blocks of 256
    win_kernel<<<(B * 36) / 256, 256, 0, stream>>>(inp, b1, b2, b3, ws,
                                                   (__half2*)vbuf);
    // phase 2: B threads, one per element
    head_kernel<<<B / 256, 256, 0, stream>>>(inp, e1, e2, E3, e3, ws,
                                             vbuf, out);
}

// Round 6
// 70.069 us; speedup vs baseline: 3.7766x; 1.7700x over previous
//
#include <hip/hip_runtime.h>
#include <hip/hip_fp16.h>

typedef _Float16 half8v __attribute__((ext_vector_type(8)));
typedef __fp16  pk16x2 __attribute__((ext_vector_type(2)));
typedef float f32x4 __attribute__((ext_vector_type(4)));

#define DEV __device__ __forceinline__
DEV float crelu(float x) { return fminf(fmaxf(x, -1.0f), 1.0f); }

DEV unsigned int pkrtz_u32(float a, float b) {
    pk16x2 p = __builtin_amdgcn_cvt_pkrtz(a, b);
    return __builtin_bit_cast(unsigned int, p);
}

// ---------------------------------------------------------------------------
// ws layout:
//   floats [0, 4790): transposed f32 tables
//     w1t [54][16] @ 0      (unused by new win, kept)
//     w2t [16][16] @ 864    (unused, kept)
//     w3t [16][2]  @ 1120   w3t[i*2+o]  = W3[o*16+i]     (win L3, s_load)
//     e1t [73][34] @ 1152   e1t[c*34+o] = E1[o*73+c]     (head)
//     e2t [34][34] @ 3634   e2t[i*34+o] = E2[o*34+i]     (head)
//   byte 19200: f16 MFMA B-fragments
//     L1frag [3][64][8] f16 (3072 B): lane l, kstep ks -> W1 in B-frag layout
//     L2frag [64][8]    f16 (1024 B)
//   byte 32768: v-buffer [B][36] half2 (9.44 MB)
// ---------------------------------------------------------------------------
__global__ void prep_kernel(const float* __restrict__ W1, const float* __restrict__ W2,
                            const float* __restrict__ W3, const float* __restrict__ E1,
                            const float* __restrict__ E2, float* __restrict__ ws) {
    int t = threadIdx.x + blockIdx.x * blockDim.x;
    if (t < 864) {
        int s = t >> 4, o = t & 15;
        ws[t] = W1[o * 54 + s];
    } else if (t < 864 + 256) {
        int u = t - 864; int i = u >> 4, o = u & 15;
        ws[t] = W2[o * 16 + i];
    } else if (t < 1120 + 32) {
        int u = t - 1120; int i = u >> 1, o = u & 1;
        ws[t] = W3[o * 16 + i];
    } else if (t < 1152 + 2482) {
        int u = t - 1152; int c = u / 34, o = u % 34;
        ws[t] = E1[o * 73 + c];
    } else if (t < 3634 + 1156) {
        int u = t - 3634; int i = u / 34, o = u % 34;
        ws[t] = E2[o * 34 + i];
    } else if (t >= 8192 && t < 8192 + 1536) {
        // layer-1 B-frag: value for lane l, kstep ks, slot j:
        //   n = l&15 (output), kg = ks*32 + 8*(l>>4) + j
        //   kg -> (ox, cy, f): kg = ox*24 + cy*8 + f ; real iff kg<72 && f<6
        _Float16* fr = (_Float16*)((char*)ws + 19200);
        int u = t - 8192;
        int ks = u >> 9, l = (u >> 3) & 63, j = u & 7;
        int n = l & 15;
        int kg = ks * 32 + ((l >> 4) << 3) + j;
        int ox = kg / 24, rem = kg - ox * 24, cy = rem >> 3, f = rem & 7;
        float v = (kg < 72 && f < 6) ? W1[n * 54 + ox * 18 + cy * 6 + f] : 0.0f;
        fr[u] = (_Float16)v;
    } else if (t >= 10240 && t < 10240 + 512) {
        // layer-2 B-frag: n = l&15, k = 8*(l>>4)+j ; real iff k<16
        _Float16* fr = (_Float16*)((char*)ws + 19200) + 1536;
        int u = t - 10240;
        int l = u >> 3, j = u & 7;
        int n = l & 15;
        int k = ((l >> 4) << 3) + j;
        float v = (k < 16) ? W2[n * 16 + k] : 0.0f;
        fr[u] = (_Float16)v;
    }
}

// ---------------------------------------------------------------------------
// Phase 1 (MFMA): one wave = 4 elements = 144 windows = 9 M-tiles of 16.
// LDS (wave-private, no barriers):
//   grid: [4 els][72 cells] half8 (cell = 8x8 grid pos, 6 ch + 2 pad)
//   h1:   [146 rows][2] half8  (h1 then overwritten in-place by h2)
// Layer1: 3 K-steps of 32 (K=54 padded to 96, pad slots have ZERO B-weights,
//         A reads in-bounds garbage). A-frag = one cell = 1 ds_read_b128.
// Layer2: 1 K-step (K=16 padded to 32, zero-B upper half).
// Layer3: VALU dot from LDS rows, packed half2 -> vbuf (layout unchanged).
// ---------------------------------------------------------------------------
__global__ __launch_bounds__(256, 3) void win_kernel(
    const float* __restrict__ inp,
    const float* __restrict__ b1, const float* __restrict__ b2,
    const float* __restrict__ b3,
    const float* __restrict__ ws, const _Float16* __restrict__ frag,
    unsigned int* __restrict__ vout)
{
    __shared__ half8v lds[4 * 580];          // 37120 B per 4-wave block
    const int tid  = threadIdx.x;
    const int wid  = tid >> 6;
    const int lane = tid & 63;
    const int baseP = (blockIdx.x * 4 + wid) * 4;    // first of 4 elements

    half8v* grid = lds + wid * 580;          // 288 half8
    half8v* h1   = grid + 288;               // 292 half8 (146 rows x 2)
    _Float16* h1h = (_Float16*)h1;

    const int r = lane & 15;                 // row within M-tile
    const int g = lane >> 4;                 // k-group

    // ---- stage 4 elements' grids (lane group es stages element es) ----
    {
        const int es = lane >> 4, m = lane & 15;
        const float* __restrict__ src = inp + (size_t)(baseP + es) * 385 + 24 * m;
        #pragma unroll
        for (int c = 0; c < 4; ++c) {
            float f0 = src[c * 6 + 0], f1 = src[c * 6 + 1], f2 = src[c * 6 + 2];
            float f3 = src[c * 6 + 3], f4 = src[c * 6 + 4], f5 = src[c * 6 + 5];
            uint4 q;
            q.x = pkrtz_u32(f0, f1);
            q.y = pkrtz_u32(f2, f3);
            q.z = pkrtz_u32(f4, f5);
            q.w = q.z;                        // pad channels 6,7 (zero-weighted)
            *reinterpret_cast<uint4*>(grid + es * 72 + 4 * m + c) = q;
        }
    }

    // ---- B-fragments (wave-shared, per-lane 16B loads) ----
    const half8v* __restrict__ fr8 = (const half8v*)frag;
    half8v B1_0 = fr8[0 * 64 + lane];
    half8v B1_1 = fr8[1 * 64 + lane];
    half8v B1_2 = fr8[2 * 64 + lane];
    half8v B2f  = fr8[3 * 64 + lane];

    // per-lane chunk offsets within a window: c = ks*4+g -> (ox, cy)
    int off[3];
    #pragma unroll
    for (int ks = 0; ks < 3; ++ks) {
        int c = ks * 4 + g;
        int ox = c / 3, cy = c - 3 * ox;     // ox may be 3 (pad, zero-B)
        off[ks] = ox * 8 + cy;
    }

    const float bias1 = b1[r];
    const float bias2 = b2[r];
    // layer-3 weights: wave-uniform s_loads
    const float* __restrict__ w3t = ws + 1120;
    const float b30 = b3[0], b31 = b3[1];

    // ---- 9 fused tiles: L1 (3 MFMA) -> h1 -> L2 (1 MFMA) -> h2 in-place ----
    int w = r, ebase = 0;                    // lane's window-in-element, e*72
    #pragma unroll
    for (int t = 0; t < 9; ++t) {
        const int x = (w * 43) >> 8;         // w/6 for w<36
        const int y = w - x * 6;
        const int cellb = ebase + x * 8 + y;

        half8v a0 = grid[cellb + off[0]];
        half8v a1 = grid[cellb + off[1]];
        half8v a2 = grid[cellb + off[2]];

        f32x4 acc = {bias1, bias1, bias1, bias1};
        acc = __builtin_amdgcn_mfma_f32_16x16x32_f16(a0, B1_0, acc, 0, 0, 0);
        acc = __builtin_amdgcn_mfma_f32_16x16x32_f16(a1, B1_1, acc, 0, 0, 0);
        acc = __builtin_amdgcn_mfma_f32_16x16x32_f16(a2, B1_2, acc, 0, 0, 0);

        // write h1: lane's 4 values are windows t*16+g*4+q, column r
        #pragma unroll
        for (int q = 0; q < 4; ++q)
            h1h[(t * 16 + g * 4 + q) * 16 + r] = (_Float16)crelu(acc[q]);

        // layer 2: A-frag = h1[row=t*16+r][k=8g..8g+7] (g>=2 reads next-row
        // garbage, zero-B)
        half8v af = h1[(t * 16 + r) * 2 + g];
        f32x4 c2 = {bias2, bias2, bias2, bias2};
        c2 = __builtin_amdgcn_mfma_f32_16x16x32_f16(af, B2f, c2, 0, 0, 0);

        // h2 overwrites h1 rows of this tile (clamped, f16)
        #pragma unroll
        for (int q = 0; q < 4; ++q)
            h1h[(t * 16 + g * 4 + q) * 16 + r] = (_Float16)crelu(c2[q]);

        // advance window bookkeeping
        w += 16;
        if (w >= 36) { w -= 36; ebase += 72; }
    }

    // ---- layer 3 (VALU): windows lane, lane+64, lane+128(<144) ----
    #pragma unroll
    for (int rep = 0; rep < 3; ++rep) {
        const int wg = lane + rep * 64;
        if (rep < 2 || lane < 16) {
            half8v ha = h1[wg * 2 + 0];
            half8v hb = h1[wg * 2 + 1];
            float v0 = b30, v1 = b31;
            #pragma unroll
            for (int i = 0; i < 8; ++i) {
                const float hv = (float)ha[i];
                v0 = fmaf(hv, w3t[i * 2 + 0], v0);
                v1 = fmaf(hv, w3t[i * 2 + 1], v1);
            }
            #pragma unroll
            for (int i = 0; i < 8; ++i) {
                const float hv = (float)hb[i];
                v0 = fmaf(hv, w3t[(8 + i) * 2 + 0], v0);
                v1 = fmaf(hv, w3t[(8 + i) * 2 + 1], v1);
            }
            vout[baseP * 36 + wg] = pkrtz_u32(crelu(v0), crelu(v1));
        }
    }
}

// ---------------------------------------------------------------------------
// Phase 2: ONE thread per element, all weight accesses lane-uniform
// (s_load / constant cache). Unchanged from round 4.
// ---------------------------------------------------------------------------
struct V8 { __half2 a, b, c, d; };   // 16 bytes = 8 halfs

__global__ __launch_bounds__(256, 1) void head_kernel(
    const float* __restrict__ inp,
    const float* __restrict__ e1, const float* __restrict__ e2,
    const float* __restrict__ E3, const float* __restrict__ e3,
    const float* __restrict__ ws, const __half* __restrict__ v,
    float* __restrict__ out)
{
    const int p = threadIdx.x + blockIdx.x * 256;   // element
    const float* __restrict__ e1t = ws + 1152;
    const float* __restrict__ e2t = ws + 3634;

    const V8* __restrict__ vp = reinterpret_cast<const V8*>(v + (size_t)p * 72);
    float vc[72];
    #pragma unroll
    for (int j = 0; j < 9; ++j) {
        const V8 q = vp[j];
        vc[8 * j + 0] = __low2float(q.a);  vc[8 * j + 1] = __high2float(q.a);
        vc[8 * j + 2] = __low2float(q.b);  vc[8 * j + 3] = __high2float(q.b);
        vc[8 * j + 4] = __low2float(q.c);  vc[8 * j + 5] = __high2float(q.c);
        vc[8 * j + 6] = __low2float(q.d);  vc[8 * j + 7] = __high2float(q.d);
    }
    const float xl = inp[(size_t)p * 385 + 384];

    float a1[34];
    #pragma unroll
    for (int o = 0; o < 34; ++o) a1[o] = e1[o];
    #pragma unroll
    for (int c = 0; c < 72; ++c) {
        const float xc = vc[c];
        const float* __restrict__ wr = e1t + c * 34;
        #pragma unroll
        for (int o = 0; o < 34; ++o) a1[o] = fmaf(xc, wr[o], a1[o]);
    }
    {
        const float* __restrict__ wr = e1t + 72 * 34;
        #pragma unroll
        for (int o = 0; o < 34; ++o) a1[o] = fmaf(xl, wr[o], a1[o]);
    }

    float a2[34];
    #pragma unroll
    for (int o = 0; o < 34; ++o) a2[o] = e2[o];
    #pragma unroll
    for (int i = 0; i < 34; ++i) {
        const float hi = crelu(a1[i]);
        const float* __restrict__ wr = e2t + i * 34;
        #pragma unroll
        for (int o = 0; o < 34; ++o) a2[o] = fmaf(hi, wr[o], a2[o]);
    }
    float rr = e3[0];
    #pragma unroll
    for (int i = 0; i < 34; ++i) rr = fmaf(crelu(a2[i]), E3[i], rr);
    out[p] = crelu(rr);
}

extern "C" void kernel_launch(void* const* d_in, const int* in_sizes, int n_in,
                              void* d_out, int out_size, void* d_ws, size_t ws_size,
                              hipStream_t stream) {
    const float* inp = (const float*)d_in[0];
    const float* W1  = (const float*)d_in[1];
    const float* b1  = (const float*)d_in[2];
    const float* W2  = (const float*)d_in[3];
    const float* b2  = (const float*)d_in[4];
    const float* W3  = (const float*)d_in[5];
    const float* b3  = (const float*)d_in[6];
    const float* E1  = (const float*)d_in[7];
    const float* e1  = (const float*)d_in[8];
    const float* E2  = (const float*)d_in[9];
    const float* e2  = (const float*)d_in[10];
    const float* E3  = (const float*)d_in[11];
    const float* e3  = (const float*)d_in[12];
    float* out = (float*)d_out;
    float* ws  = (float*)d_ws;
    const _Float16* frag = (const _Float16*)((const char*)d_ws + 19200);
    __half* vbuf = (__half*)((char*)d_ws + 32768);

    // prep: f32 tables + f16 B-frags (threads up to 10752)
    prep_kernel<<<42, 256, 0, stream>>>(W1, W2, W3, E1, E2, ws);

    const int B = 65536;
    // phase 1: 4096 blocks x 4 waves x 4 elements = 65536
    win_kernel<<<B / 16, 256, 0, stream>>>(inp, b1, b2, b3, ws, frag,
                                           (unsigned int*)vbuf);
    // phase 2: one thread per element
    head_kernel<<<B / 256, 256, 0, stream>>>(inp, e1, e2, E3, e3, ws,
                                             vbuf, out);
}